// Round 7
// baseline (423.826 us; speedup 1.0000x reference)
//
#include <hip/hip_runtime.h>
#include <hip/hip_bf16.h>

#define NH 16
#define DK 64
#define BB 8
#define SS 1024
#define DM 1024
#define MTOT (BB * SS) /* 8192 */

typedef float f4v __attribute__((ext_vector_type(4)));
typedef float f16v __attribute__((ext_vector_type(16)));
typedef short s16v8 __attribute__((ext_vector_type(8)));
typedef unsigned short u16v4 __attribute__((ext_vector_type(4)));
typedef unsigned short u16v8 __attribute__((ext_vector_type(8)));

// 2^x via v_exp_f32 (avoids glibc __exp2f macro collision)
#define EXP2F(x) __builtin_amdgcn_exp2f(x)

// round-to-nearest-even f32 -> bf16 bits
__device__ __forceinline__ unsigned short f2bf(float x) {
    unsigned int u = __float_as_uint(x);
    u += 0x7FFFu + ((u >> 16) & 1u);
    return (unsigned short)(u >> 16);
}

// pack two f32 -> bf16x2 in a u32 (lo in low half), RTNE
__device__ __forceinline__ unsigned int packbf2(float lo, float hi) {
    return ((unsigned int)f2bf(hi) << 16) | f2bf(lo);
}

// async global->LDS, 16B per lane (dest must be linear in lane order)
__device__ __forceinline__ void gload16(const void* g, void* l) {
    __builtin_amdgcn_global_load_lds(
        (const __attribute__((address_space(1))) void*)g,
        (__attribute__((address_space(3))) void*)l, 16, 0, 0);
}

// ---------------------------------------------------------------------------
// Convert all fp32 inputs to bf16, concatenated in ws:
// [query(8M) key(8M) value(8M) wq(1M) wk(1M) wv(1M) wo(1M)] elements.
// ---------------------------------------------------------------------------
struct Src7 { const float* p[7]; };

__global__ __launch_bounds__(256) void cvt_all(Src7 sp, unsigned short* __restrict__ dst) {
    const size_t e = ((size_t)blockIdx.x * 256 + threadIdx.x) * 8;
    const int unit = (int)(e >> 20);
    int t; size_t base;
    if (unit < 8)       { t = 0; base = 0; }
    else if (unit < 16) { t = 1; base = (size_t)8 << 20; }
    else if (unit < 24) { t = 2; base = (size_t)16 << 20; }
    else                { t = 3 + (unit - 24); base = (size_t)unit << 20; }
    const float* s = sp.p[t] + (e - base);
    f4v a = *(const f4v*)s;
    f4v b = *(const f4v*)(s + 4);
    u16v8 o;
    o[0] = f2bf(a[0]); o[1] = f2bf(a[1]); o[2] = f2bf(a[2]); o[3] = f2bf(a[3]);
    o[4] = f2bf(b[0]); o[5] = f2bf(b[1]); o[6] = f2bf(b[2]); o[7] = f2bf(b[3]);
    *(u16v8*)(dst + e) = o;
}

// ---------------------------------------------------------------------------
// Fused QKV GEMM: for z in {0,1,2}: Y = X_z @ W_z^T + b_z, K = 1024.
// Grid (64 m-tiles, 8 n-tiles, 3): XCD = m-tile%8 -> each XCD keeps its
// A-panels + all weight panels L2-resident (was: XCD = n-tile -> A re-read).
// z=0,1 (Q,K): bf16 headed out [b,h,s,d]. z=2 (V): bf16 TRANSPOSED out
// [b,h,d,s] (fuses the V transpose into the epilogue).
// ---------------------------------------------------------------------------
struct QkvArgs {
    const unsigned short* X[3];
    const unsigned short* W[3];
    const float* bias[3];
    unsigned short* Y[3];
};

__global__ __launch_bounds__(256) void gemm_qkv(QkvArgs a) {
    __shared__ unsigned short As[128 * 32];
    __shared__ unsigned short Bs[128 * 32];
    const int z = blockIdx.z;
    const unsigned short* X = a.X[z];
    const unsigned short* W = a.W[z];
    const float* bias = a.bias[z];
    unsigned short* Y = a.Y[z];

    const int tid = threadIdx.x;
    const int wv = tid >> 6, l = tid & 63;
    const int lq = l & 15, g = l >> 4;
    const int wr = wv >> 1, wc = wv & 1;
    const int m0 = blockIdx.x * 128, n0 = blockIdx.y * 128;

    f4v acc[4][4];
#pragma unroll
    for (int i = 0; i < 4; ++i)
#pragma unroll
        for (int j = 0; j < 4; ++j) acc[i][j] = (f4v){0.f, 0.f, 0.f, 0.f};

    for (int kt = 0; kt < DM / 32; ++kt) {
        const int k0 = kt * 32;
        __syncthreads();
#pragma unroll
        for (int p = 0; p < 2; ++p) {
            const int u = p * 256 + tid;
            const int row = u >> 2, kc = u & 3;
            gload16(X + (size_t)(m0 + row) * DM + k0 + kc * 8, As + (size_t)u * 8);
            gload16(W + (size_t)(n0 + row) * DM + k0 + kc * 8, Bs + (size_t)u * 8);
        }
        __syncthreads();

        s16v8 av[4], bv[4];
#pragma unroll
        for (int i = 0; i < 4; ++i)
            av[i] = *(const s16v8*)(As + (wr * 64 + i * 16 + lq) * 32 + g * 8);
#pragma unroll
        for (int j = 0; j < 4; ++j)
            bv[j] = *(const s16v8*)(Bs + (wc * 64 + j * 16 + lq) * 32 + g * 8);
#pragma unroll
        for (int i = 0; i < 4; ++i)
#pragma unroll
            for (int j = 0; j < 4; ++j)
                acc[i][j] = __builtin_amdgcn_mfma_f32_16x16x32_bf16(av[i], bv[j], acc[i][j], 0, 0, 0);
    }

    // epilogue: D layout col = lane&15, row = (lane>>4)*4 + reg
#pragma unroll
    for (int j = 0; j < 4; ++j) {
        const int col = n0 + wc * 64 + j * 16 + lq;
        const float bvl = bias[col];
#pragma unroll
        for (int i = 0; i < 4; ++i) {
            const int row0 = m0 + wr * 64 + i * 16 + g * 4;
            if (z < 2) {
#pragma unroll
                for (int r = 0; r < 4; ++r) {
                    const int row = row0 + r;
                    const int b_ = row >> 10, s_ = row & (SS - 1);
                    const int h_ = col >> 6, d_ = col & (DK - 1);
                    Y[((size_t)(b_ * NH + h_) * SS + s_) * DK + d_] = f2bf(acc[i][j][r] + bvl);
                }
            } else {
                // V: transposed [b,h,d,s] — rows r are consecutive s -> 8B store
                const int b_ = row0 >> 10, s0_ = row0 & (SS - 1);
                const int h_ = col >> 6, d_ = col & (DK - 1);
                u16v4 o;
#pragma unroll
                for (int r = 0; r < 4; ++r) o[r] = f2bf(acc[i][j][r] + bvl);
                *(u16v4*)&Y[((size_t)(b_ * NH + h_) * DK + d_) * SS + s0_] = o;
            }
        }
    }
}

// ---------------------------------------------------------------------------
// Final GEMM: out[M,DM] fp32 = ctx @ W_o^T + b_o.  Grid (64 m, 8 n).
// ---------------------------------------------------------------------------
__global__ __launch_bounds__(256) void gemm_out(const unsigned short* __restrict__ X,
                                                const unsigned short* __restrict__ W,
                                                const float* __restrict__ bias,
                                                float* __restrict__ Y) {
    __shared__ unsigned short As[128 * 32];
    __shared__ unsigned short Bs[128 * 32];
    const int tid = threadIdx.x;
    const int wv = tid >> 6, l = tid & 63;
    const int lq = l & 15, g = l >> 4;
    const int wr = wv >> 1, wc = wv & 1;
    const int m0 = blockIdx.x * 128, n0 = blockIdx.y * 128;

    f4v acc[4][4];
#pragma unroll
    for (int i = 0; i < 4; ++i)
#pragma unroll
        for (int j = 0; j < 4; ++j) acc[i][j] = (f4v){0.f, 0.f, 0.f, 0.f};

    for (int kt = 0; kt < DM / 32; ++kt) {
        const int k0 = kt * 32;
        __syncthreads();
#pragma unroll
        for (int p = 0; p < 2; ++p) {
            const int u = p * 256 + tid;
            const int row = u >> 2, kc = u & 3;
            gload16(X + (size_t)(m0 + row) * DM + k0 + kc * 8, As + (size_t)u * 8);
            gload16(W + (size_t)(n0 + row) * DM + k0 + kc * 8, Bs + (size_t)u * 8);
        }
        __syncthreads();

        s16v8 av[4], bv[4];
#pragma unroll
        for (int i = 0; i < 4; ++i)
            av[i] = *(const s16v8*)(As + (wr * 64 + i * 16 + lq) * 32 + g * 8);
#pragma unroll
        for (int j = 0; j < 4; ++j)
            bv[j] = *(const s16v8*)(Bs + (wc * 64 + j * 16 + lq) * 32 + g * 8);
#pragma unroll
        for (int i = 0; i < 4; ++i)
#pragma unroll
            for (int j = 0; j < 4; ++j)
                acc[i][j] = __builtin_amdgcn_mfma_f32_16x16x32_bf16(av[i], bv[j], acc[i][j], 0, 0, 0);
    }

#pragma unroll
    for (int j = 0; j < 4; ++j) {
        const int col = n0 + wc * 64 + j * 16 + lq;
        const float bvl = bias[col];
#pragma unroll
        for (int i = 0; i < 4; ++i) {
#pragma unroll
            for (int r = 0; r < 4; ++r) {
                const int row = m0 + wr * 64 + i * 16 + g * 4 + r;
                Y[(size_t)row * DM + col] = acc[i][j][r] + bvl;
            }
        }
    }
}

// ---------------------------------------------------------------------------
// Flash attention v3: swapped-operand 32x32 MFMA, register-rotated K pipeline.
// Qp,Kp: [b,h,s,64]; Vt: [b,h,64,s]. 256 thr = 4 INDEPENDENT waves (no
// barriers in the loop, no LDS staging). Wave owns 32 q-rows.
// Pipeline: iter t issues V(t) loads, then K(t+1) loads into the spare reg
// buffer, THEN computes QK^T with K(t) (loaded one iter ago) -> global-load
// latency hides under softmax+PV. Compiler's dependency-tracked vmcnt keeps
// K(t+1)/V(t) in flight across the compute.
// Softmax lane-local (S^T = mfma(K,Q), col=q=lane&31); defer-max T13;
// P^T built in-register (bf16 pack + shfl_xor(32)); PV swapped.
// Epilogue: O^T bounced through per-wave XOR-swizzled LDS tile -> each lane
// stores 64B contiguous per ctx row (fixes the 3.7x write amplification of
// the 8B scattered stores).
// Grid (128 bh, 8 qblk): XCD = bh%8 -> all 8 q-blocks of a head on one XCD.
// ---------------------------------------------------------------------------
__device__ __forceinline__ void attn_iter(int t, int tn,
                                          const unsigned short* __restrict__ Kb,
                                          const unsigned short* __restrict__ Vb,
                                          int l31, int hi,
                                          const s16v8 (&qf)[4],
                                          s16v8 (&ku)[2][4],   // K frags for tile t (already in regs)
                                          s16v8 (&kl)[2][4],   // K frags to load for tile tn
                                          f16v& O0, f16v& O1, float& me, float& lr) {
    const float C = 0.18033688011112042f;  // log2(e)/8 (1/sqrt(64) folded)

    // issue V(t) loads first, then K(tn) loads: PV's wait leaves K(tn) in flight
    s16v8 vf[2][4];
#pragma unroll
    for (int db = 0; db < 2; ++db)
#pragma unroll
        for (int ksg = 0; ksg < 4; ++ksg)
            vf[db][ksg] = *(const s16v8*)(Vb + (size_t)(db * 32 + l31) * SS + t * 64 + ksg * 16 + hi * 8);
#pragma unroll
    for (int ks = 0; ks < 2; ++ks)
#pragma unroll
        for (int kd = 0; kd < 4; ++kd)
            kl[ks][kd] = *(const s16v8*)(Kb + (size_t)(tn * 64 + ks * 32 + l31) * DK + kd * 16 + hi * 8);

    // S^T = K @ Q : lane holds scores for q, keys (r&3)+8*(r>>2)+4*hi (+32*ks)
    f16v s0, s1;
#pragma unroll
    for (int r = 0; r < 16; ++r) { s0[r] = 0.f; s1[r] = 0.f; }
#pragma unroll
    for (int kd = 0; kd < 4; ++kd) {
        s0 = __builtin_amdgcn_mfma_f32_32x32x16_bf16(ku[0][kd], qf[kd], s0, 0, 0, 0);
        s1 = __builtin_amdgcn_mfma_f32_32x32x16_bf16(ku[1][kd], qf[kd], s1, 0, 0, 0);
    }

    // lane-local row max (raw domain), combine halves with one shfl
    float mx = s0[0];
#pragma unroll
    for (int r = 1; r < 16; ++r) mx = fmaxf(mx, s0[r]);
#pragma unroll
    for (int r = 0; r < 16; ++r) mx = fmaxf(mx, s1[r]);
    mx = fmaxf(mx, __shfl_xor(mx, 32));
    const float mxl = mx * C;

    // defer-max (T13): only rescale when max grew by > 8 (2^8 headroom)
    const bool need = !__all(mxl - me <= 8.0f);
    float corr = 1.0f;
    if (need) {
        const float mnew = fmaxf(me, mxl);
        corr = EXP2F(me - mnew);
        me = mnew;
    }

    // P = 2^(s*C - me), row-sum; overwrite s-regs with p
    float rs = 0.f;
#pragma unroll
    for (int r = 0; r < 16; ++r) { s0[r] = EXP2F(__fmaf_rn(s0[r], C, -me)); rs += s0[r]; }
#pragma unroll
    for (int r = 0; r < 16; ++r) { s1[r] = EXP2F(__fmaf_rn(s1[r], C, -me)); rs += s1[r]; }
    rs += __shfl_xor(rs, 32);
    if (need) {
        lr = lr * corr + rs;
#pragma unroll
        for (int r = 0; r < 16; ++r) { O0[r] *= corr; O1[r] *= corr; }
    } else {
        lr += rs;
    }

    // Build P^T B-frags (col=q, k=key): pack reg-pairs to bf16x2,
    // exchange halves via shfl_xor(32), select own/partner per hi.
    s16v8 pb[2][2];
#pragma unroll
    for (int ks = 0; ks < 2; ++ks) {
        unsigned int u[8], su[8];
#pragma unroll
        for (int i = 0; i < 8; ++i) {
            const float plo = (ks == 0) ? s0[2 * i] : s1[2 * i];
            const float phi = (ks == 0) ? s0[2 * i + 1] : s1[2 * i + 1];
            u[i] = packbf2(plo, phi);
        }
#pragma unroll
        for (int i = 0; i < 8; ++i) su[i] = (unsigned int)__shfl_xor((int)u[i], 32);
#pragma unroll
        for (int kk = 0; kk < 2; ++kk) {
            const int base = 4 * kk + 2 * hi;
            union { unsigned int w[4]; s16v8 s; } f;
            f.w[0] = hi ? su[base] : u[base];
            f.w[1] = hi ? su[base + 1] : u[base + 1];
            f.w[2] = hi ? u[base] : su[base];
            f.w[3] = hi ? u[base + 1] : su[base + 1];
            pb[ks][kk] = f.s;
        }
    }

    // O^T += V^T @ P^T  (k = 16 keys per mfma; ksg = ks*2+kk)
#pragma unroll
    for (int ksg = 0; ksg < 4; ++ksg) {
        O0 = __builtin_amdgcn_mfma_f32_32x32x16_bf16(vf[0][ksg], pb[ksg >> 1][ksg & 1], O0, 0, 0, 0);
        O1 = __builtin_amdgcn_mfma_f32_32x32x16_bf16(vf[1][ksg], pb[ksg >> 1][ksg & 1], O1, 0, 0, 0);
    }
}

__global__ __launch_bounds__(256, 2) void attn_mfma32(const unsigned short* __restrict__ Qp,
                                                      const unsigned short* __restrict__ Kp,
                                                      const unsigned short* __restrict__ Vt,
                                                      unsigned short* __restrict__ ctx) {
    __shared__ unsigned short Ob[4][2048];  // per-wave 32 rows x 64 bf16, XOR-swizzled
    const int tid = threadIdx.x;
    const int wv = tid >> 6;
    const int l = tid & 63;
    const int l31 = l & 31, hi = l >> 5;
    const int bh = blockIdx.x;              // XCD = bh%8: head's q-blocks share an XCD
    const int qblk = blockIdx.y;
    const int q = qblk * 128 + wv * 32 + l31;

    // Q B-frags: col=q=lane&31, k = d = kd*16 + hi*8 + e
    const unsigned short* Qrow = Qp + ((size_t)bh * SS + q) * DK + hi * 8;
    s16v8 qf[4];
#pragma unroll
    for (int kd = 0; kd < 4; ++kd) qf[kd] = *(const s16v8*)(Qrow + kd * 16);

    const unsigned short* Kb = Kp + (size_t)bh * SS * DK;
    const unsigned short* Vb = Vt + (size_t)bh * DK * SS;

    f16v O0, O1;  // O^T accum: rows d = db*32 + (r&3)+8*(r>>2)+4*hi, col q
#pragma unroll
    for (int r = 0; r < 16; ++r) { O0[r] = 0.f; O1[r] = 0.f; }
    float me = -1e30f;
    float lr = 0.f;

    // prologue: K(0) into kA
    s16v8 kA[2][4], kB[2][4];
#pragma unroll
    for (int ks = 0; ks < 2; ++ks)
#pragma unroll
        for (int kd = 0; kd < 4; ++kd)
            kA[ks][kd] = *(const s16v8*)(Kb + (size_t)(ks * 32 + l31) * DK + kd * 16 + hi * 8);

    for (int tt = 0; tt < 8; ++tt) {
        const int t0 = 2 * tt, t1 = 2 * tt + 1;
        attn_iter(t0, t1, Kb, Vb, l31, hi, qf, kA, kB, O0, O1, me, lr);
        attn_iter(t1, (t1 + 1 < 16) ? t1 + 1 : 15, Kb, Vb, l31, hi, qf, kB, kA, O0, O1, me, lr);
    }

    // ---- epilogue: normalize, bounce through LDS, coalesced 64B/lane stores
    const float inv = 1.0f / lr;
    unsigned short* mybuf = Ob[wv];
#pragma unroll
    for (int db = 0; db < 2; ++db) {
        const f16v Ocur = db ? O1 : O0;
#pragma unroll
        for (int g2 = 0; g2 < 4; ++g2) {
            uint2 w;
            w.x = packbf2(Ocur[4 * g2 + 0] * inv, Ocur[4 * g2 + 1] * inv);
            w.y = packbf2(Ocur[4 * g2 + 2] * inv, Ocur[4 * g2 + 3] * inv);
            const int off = db * 64 + g2 * 16 + hi * 8;            // byte offset in 128B row
            *(uint2*)((char*)mybuf + l31 * 128 + (off ^ ((l31 & 7) << 4))) = w;
        }
    }
    __syncthreads();  // orders per-wave LDS write->read (wave-local, cheap)

    const int r = l >> 1, h2 = l & 1;
    const int qrow = qblk * 128 + wv * 32 + r;
    const int b_ = bh >> 4, h_ = bh & 15;
    unsigned short* crow = ctx + ((size_t)b_ * SS + qrow) * DM + h_ * DK + h2 * 32;
#pragma unroll
    for (int j = 0; j < 4; ++j) {
        const int off = (h2 * 64 + j * 16) ^ ((r & 7) << 4);
        u16v8 v = *(const u16v8*)((const char*)mybuf + r * 128 + off);
        *(u16v8*)(crow + j * 8) = v;
    }
}

// ---------------------------------------------------------------------------
extern "C" void kernel_launch(void* const* d_in, const int* in_sizes, int n_in,
                              void* d_out, int out_size, void* d_ws, size_t ws_size,
                              hipStream_t stream) {
    const float* query = (const float*)d_in[0];
    const float* key_  = (const float*)d_in[1];
    const float* value = (const float*)d_in[2];
    const float* w_q = (const float*)d_in[3];
    const float* b_q = (const float*)d_in[4];
    const float* w_k = (const float*)d_in[5];
    const float* b_k = (const float*)d_in[6];
    const float* w_v = (const float*)d_in[7];
    const float* b_v = (const float*)d_in[8];
    const float* w_o = (const float*)d_in[9];
    const float* b_o = (const float*)d_in[10];

    unsigned short* ws = (unsigned short*)d_ws;
    const size_t NX = (size_t)MTOT * DM;  // 8,388,608
    const size_t NW = (size_t)DM * DM;    // 1,048,576
    unsigned short* xq  = ws;
    unsigned short* xk  = xq + NX;
    unsigned short* xv  = xk + NX;
    unsigned short* wqb = xv + NX;
    unsigned short* wkb = wqb + NW;
    unsigned short* wvb = wkb + NW;
    unsigned short* wob = wvb + NW;
    unsigned short* Qp  = wob + NW;
    unsigned short* Kp  = Qp + NX;
    unsigned short* VpT = Kp + NX;
    unsigned short* ctx = xq;  // alias: xq dead after gemm_qkv
    // high-water: 6*NX + 4*NW = 104 MB

    Src7 sp;
    sp.p[0] = query; sp.p[1] = key_; sp.p[2] = value;
    sp.p[3] = w_q; sp.p[4] = w_k; sp.p[5] = w_v; sp.p[6] = w_o;
    cvt_all<<<14336, 256, 0, stream>>>(sp, ws);

    QkvArgs qa;
    qa.X[0] = xq;  qa.X[1] = xk;  qa.X[2] = xv;
    qa.W[0] = wqb; qa.W[1] = wkb; qa.W[2] = wvb;
    qa.bias[0] = b_q; qa.bias[1] = b_k; qa.bias[2] = b_v;
    qa.Y[0] = Qp; qa.Y[1] = Kp; qa.Y[2] = VpT;
    gemm_qkv<<<dim3(MTOT / 128, DM / 128, 3), 256, 0, stream>>>(qa);

    attn_mfma32<<<dim3(BB * NH, SS / 128), 256, 0, stream>>>(Qp, Kp, VpT, ctx);

    gemm_out<<<dim3(MTOT / 128, DM / 128), 256, 0, stream>>>(ctx, wob, b_o, (float*)d_out);
}

// Round 8
// 362.877 us; speedup vs baseline: 1.1680x; 1.1680x over previous
//
#include <hip/hip_runtime.h>
#include <hip/hip_bf16.h>

#define NH 16
#define DK 64
#define BB 8
#define SS 1024
#define DM 1024
#define MTOT (BB * SS) /* 8192 */

typedef float f4v __attribute__((ext_vector_type(4)));
typedef float f16v __attribute__((ext_vector_type(16)));
typedef short s16v8 __attribute__((ext_vector_type(8)));
typedef unsigned short u16v4 __attribute__((ext_vector_type(4)));
typedef unsigned short u16v8 __attribute__((ext_vector_type(8)));

// 2^x via v_exp_f32 (avoids glibc __exp2f macro collision)
#define EXP2F(x) __builtin_amdgcn_exp2f(x)
// s_waitcnt encodings: simm = vmcnt[3:0] | expcnt<<4 | lgkmcnt<<8 (unconstrained: 15/7/15)
#define WAIT_VM2() __builtin_amdgcn_s_waitcnt(0x0F72)
#define WAIT_VM0() __builtin_amdgcn_s_waitcnt(0x0F70)

// round-to-nearest-even f32 -> bf16 bits
__device__ __forceinline__ unsigned short f2bf(float x) {
    unsigned int u = __float_as_uint(x);
    u += 0x7FFFu + ((u >> 16) & 1u);
    return (unsigned short)(u >> 16);
}

// pack two f32 -> bf16x2 in a u32 (lo in low half), RTNE
__device__ __forceinline__ unsigned int packbf2(float lo, float hi) {
    return ((unsigned int)f2bf(hi) << 16) | f2bf(lo);
}

// async global->LDS, 16B per lane (dest must be linear in lane order)
__device__ __forceinline__ void gload16(const void* g, void* l) {
    __builtin_amdgcn_global_load_lds(
        (const __attribute__((address_space(1))) void*)g,
        (__attribute__((address_space(3))) void*)l, 16, 0, 0);
}

// ---------------------------------------------------------------------------
// Convert all fp32 inputs to bf16, concatenated in ws:
// [query(8M) key(8M) value(8M) wq(1M) wk(1M) wv(1M) wo(1M)] elements.
// ---------------------------------------------------------------------------
struct Src7 { const float* p[7]; };

__global__ __launch_bounds__(256) void cvt_all(Src7 sp, unsigned short* __restrict__ dst) {
    const size_t e = ((size_t)blockIdx.x * 256 + threadIdx.x) * 8;
    const int unit = (int)(e >> 20);
    int t; size_t base;
    if (unit < 8)       { t = 0; base = 0; }
    else if (unit < 16) { t = 1; base = (size_t)8 << 20; }
    else if (unit < 24) { t = 2; base = (size_t)16 << 20; }
    else                { t = 3 + (unit - 24); base = (size_t)unit << 20; }
    const float* s = sp.p[t] + (e - base);
    f4v a = *(const f4v*)s;
    f4v b = *(const f4v*)(s + 4);
    u16v8 o;
    o[0] = f2bf(a[0]); o[1] = f2bf(a[1]); o[2] = f2bf(a[2]); o[3] = f2bf(a[3]);
    o[4] = f2bf(b[0]); o[5] = f2bf(b[1]); o[6] = f2bf(b[2]); o[7] = f2bf(b[3]);
    *(u16v8*)(dst + e) = o;
}

// ---------------------------------------------------------------------------
// Fused QKV GEMM: for z in {0,1,2}: Y = X_z @ W_z^T + b_z, K = 1024.
// Grid (64 m-tiles, 8 n-tiles, 3): XCD = m-tile%8 -> A-panels L2-resident.
// z=0,1 (Q,K): bf16 headed out [b,h,s,d]. z=2 (V): bf16 TRANSPOSED out
// [b,h,d,s] (fuses the V transpose into the epilogue).
// ---------------------------------------------------------------------------
struct QkvArgs {
    const unsigned short* X[3];
    const unsigned short* W[3];
    const float* bias[3];
    unsigned short* Y[3];
};

__global__ __launch_bounds__(256) void gemm_qkv(QkvArgs a) {
    __shared__ unsigned short As[128 * 32];
    __shared__ unsigned short Bs[128 * 32];
    const int z = blockIdx.z;
    const unsigned short* X = a.X[z];
    const unsigned short* W = a.W[z];
    const float* bias = a.bias[z];
    unsigned short* Y = a.Y[z];

    const int tid = threadIdx.x;
    const int wv = tid >> 6, l = tid & 63;
    const int lq = l & 15, g = l >> 4;
    const int wr = wv >> 1, wc = wv & 1;
    const int m0 = blockIdx.x * 128, n0 = blockIdx.y * 128;

    f4v acc[4][4];
#pragma unroll
    for (int i = 0; i < 4; ++i)
#pragma unroll
        for (int j = 0; j < 4; ++j) acc[i][j] = (f4v){0.f, 0.f, 0.f, 0.f};

    for (int kt = 0; kt < DM / 32; ++kt) {
        const int k0 = kt * 32;
        __syncthreads();
#pragma unroll
        for (int p = 0; p < 2; ++p) {
            const int u = p * 256 + tid;
            const int row = u >> 2, kc = u & 3;
            gload16(X + (size_t)(m0 + row) * DM + k0 + kc * 8, As + (size_t)u * 8);
            gload16(W + (size_t)(n0 + row) * DM + k0 + kc * 8, Bs + (size_t)u * 8);
        }
        __syncthreads();

        s16v8 av[4], bv[4];
#pragma unroll
        for (int i = 0; i < 4; ++i)
            av[i] = *(const s16v8*)(As + (wr * 64 + i * 16 + lq) * 32 + g * 8);
#pragma unroll
        for (int j = 0; j < 4; ++j)
            bv[j] = *(const s16v8*)(Bs + (wc * 64 + j * 16 + lq) * 32 + g * 8);
#pragma unroll
        for (int i = 0; i < 4; ++i)
#pragma unroll
            for (int j = 0; j < 4; ++j)
                acc[i][j] = __builtin_amdgcn_mfma_f32_16x16x32_bf16(av[i], bv[j], acc[i][j], 0, 0, 0);
    }

    // epilogue: D layout col = lane&15, row = (lane>>4)*4 + reg
#pragma unroll
    for (int j = 0; j < 4; ++j) {
        const int col = n0 + wc * 64 + j * 16 + lq;
        const float bvl = bias[col];
#pragma unroll
        for (int i = 0; i < 4; ++i) {
            const int row0 = m0 + wr * 64 + i * 16 + g * 4;
            if (z < 2) {
#pragma unroll
                for (int r = 0; r < 4; ++r) {
                    const int row = row0 + r;
                    const int b_ = row >> 10, s_ = row & (SS - 1);
                    const int h_ = col >> 6, d_ = col & (DK - 1);
                    Y[((size_t)(b_ * NH + h_) * SS + s_) * DK + d_] = f2bf(acc[i][j][r] + bvl);
                }
            } else {
                // V: transposed [b,h,d,s] — rows r are consecutive s -> 8B store
                const int b_ = row0 >> 10, s0_ = row0 & (SS - 1);
                const int h_ = col >> 6, d_ = col & (DK - 1);
                u16v4 o;
#pragma unroll
                for (int r = 0; r < 4; ++r) o[r] = f2bf(acc[i][j][r] + bvl);
                *(u16v4*)&Y[((size_t)(b_ * NH + h_) * DK + d_) * SS + s0_] = o;
            }
        }
    }
}

// ---------------------------------------------------------------------------
// Final GEMM: out[M,DM] fp32 = ctx @ W_o^T + b_o.  Grid (64 m, 8 n).
// ---------------------------------------------------------------------------
__global__ __launch_bounds__(256) void gemm_out(const unsigned short* __restrict__ X,
                                                const unsigned short* __restrict__ W,
                                                const float* __restrict__ bias,
                                                float* __restrict__ Y) {
    __shared__ unsigned short As[128 * 32];
    __shared__ unsigned short Bs[128 * 32];
    const int tid = threadIdx.x;
    const int wv = tid >> 6, l = tid & 63;
    const int lq = l & 15, g = l >> 4;
    const int wr = wv >> 1, wc = wv & 1;
    const int m0 = blockIdx.x * 128, n0 = blockIdx.y * 128;

    f4v acc[4][4];
#pragma unroll
    for (int i = 0; i < 4; ++i)
#pragma unroll
        for (int j = 0; j < 4; ++j) acc[i][j] = (f4v){0.f, 0.f, 0.f, 0.f};

    for (int kt = 0; kt < DM / 32; ++kt) {
        const int k0 = kt * 32;
        __syncthreads();
#pragma unroll
        for (int p = 0; p < 2; ++p) {
            const int u = p * 256 + tid;
            const int row = u >> 2, kc = u & 3;
            gload16(X + (size_t)(m0 + row) * DM + k0 + kc * 8, As + (size_t)u * 8);
            gload16(W + (size_t)(n0 + row) * DM + k0 + kc * 8, Bs + (size_t)u * 8);
        }
        __syncthreads();

        s16v8 av[4], bv[4];
#pragma unroll
        for (int i = 0; i < 4; ++i)
            av[i] = *(const s16v8*)(As + (wr * 64 + i * 16 + lq) * 32 + g * 8);
#pragma unroll
        for (int j = 0; j < 4; ++j)
            bv[j] = *(const s16v8*)(Bs + (wc * 64 + j * 16 + lq) * 32 + g * 8);
#pragma unroll
        for (int i = 0; i < 4; ++i)
#pragma unroll
            for (int j = 0; j < 4; ++j)
                acc[i][j] = __builtin_amdgcn_mfma_f32_16x16x32_bf16(av[i], bv[j], acc[i][j], 0, 0, 0);
    }

#pragma unroll
    for (int j = 0; j < 4; ++j) {
        const int col = n0 + wc * 64 + j * 16 + lq;
        const float bvl = bias[col];
#pragma unroll
        for (int i = 0; i < 4; ++i) {
#pragma unroll
            for (int r = 0; r < 4; ++r) {
                const int row = m0 + wr * 64 + i * 16 + g * 4 + r;
                Y[(size_t)row * DM + col] = acc[i][j][r] + bvl;
            }
        }
    }
}

// ---------------------------------------------------------------------------
// Flash attention v4: R6's proven LDS-staged swapped-operand 32x32 structure,
// widened to 8 waves / 512 threads (256 q-rows per block) for occupancy:
// grid (128 bh, 4 qblk) = 512 blocks = exactly 2/CU -> 16 waves/CU.
// K/V double-buffered via global_load_lds, counted s_waitcnt vmcnt(2)
// (each thread stages 1 K-unit + 1 V-unit per tile). All frag layouts,
// swapped softmax (S^T = mfma(K,Q)), defer-max, P^T shuffle identical to R6.
// Epilogue: O^T bounced through the (dead) K/V LDS (XOR-swizzled, per-wave
// 4KB) -> 16B-coalesced ctx stores (fixes R6's 3.7x write amplification).
// ---------------------------------------------------------------------------
__global__ __launch_bounds__(512, 4) void attn_mfma32(const unsigned short* __restrict__ Qp,
                                                      const unsigned short* __restrict__ Kp,
                                                      const unsigned short* __restrict__ Vt,
                                                      unsigned short* __restrict__ ctx) {
    __shared__ unsigned short Sh[16384];  // 32KB: K dbuf [0,8K), V dbuf [8K,16K) u16
    const int tid = threadIdx.x;
    const int wv = tid >> 6;              // 0..7
    const int l = tid & 63;
    const int l31 = l & 31, hi = l >> 5;
    const int bh = blockIdx.x;            // XCD = bh%8: head's blocks share an XCD
    const int qblk = blockIdx.y;
    const int q = qblk * 256 + wv * 32 + l31;
    const float C = 0.18033688011112042f; // log2(e)/8 (1/sqrt(64) folded)

#define ShK(buf) (Sh + (buf) * 4096)
#define ShV(buf) (Sh + 8192 + (buf) * 4096)

    // Q B-frags: col=q=lane&31, k = d = kd*16 + hi*8 + e
    const unsigned short* Qrow = Qp + ((size_t)bh * SS + q) * DK + hi * 8;
    s16v8 qf[4];
#pragma unroll
    for (int kd = 0; kd < 4; ++kd) qf[kd] = *(const s16v8*)(Qrow + kd * 16);

    const unsigned short* Kb = Kp + (size_t)bh * SS * DK;
    const unsigned short* Vb = Vt + (size_t)bh * DK * SS;

    // stage tile t: 512 16B-units each for K and V, 1 of each per thread;
    // unit u -> K[t*64 + (u&63)][(u>>6)*8..] and Vt[u&63][t*64+(u>>6)*8..]
#define STAGE(buf, t)                                                       \
    {                                                                       \
        const int u = tid;                                                  \
        gload16(Kb + (size_t)((t) * 64 + (u & 63)) * DK + (u >> 6) * 8,     \
                ShK(buf) + (size_t)u * 8);                                  \
        gload16(Vb + (size_t)(u & 63) * SS + (t) * 64 + (u >> 6) * 8,       \
                ShV(buf) + (size_t)u * 8);                                  \
    }

    f16v O0, O1;  // O^T accum: rows d = db*32 + (r&3)+8*(r>>2)+4*hi, col q
#pragma unroll
    for (int r = 0; r < 16; ++r) { O0[r] = 0.f; O1[r] = 0.f; }
    float me = -1e30f;  // running max, log2 domain
    float lr = 0.f;     // running denom

    STAGE(0, 0);  // prologue: 2 loads/thread in flight
    int cur = 0;

    for (int t = 0; t < SS / 64; ++t) {
        const int tn = (t < SS / 64 - 1) ? t + 1 : t;  // clamp: uniform vmcnt
        STAGE(cur ^ 1, tn);   // next tile's loads fly under this tile's compute
        WAIT_VM2();           // tile-t batch (issued last iter) has landed
        __builtin_amdgcn_s_barrier();

        // K A-frags: row=key=ks*32+l31, kunit=2*kd+hi
        s16v8 kf[2][4];
#pragma unroll
        for (int ks = 0; ks < 2; ++ks)
#pragma unroll
            for (int kd = 0; kd < 4; ++kd)
                kf[ks][kd] = *(const s16v8*)(ShK(cur) + (((2 * kd + hi) * 64) + ks * 32 + l31) * 8);
        // V^T A-frags: row=d=db*32+l31, keyunit=2*ksg+hi
        s16v8 vf[2][4];
#pragma unroll
        for (int db = 0; db < 2; ++db)
#pragma unroll
            for (int ksg = 0; ksg < 4; ++ksg)
                vf[db][ksg] = *(const s16v8*)(ShV(cur) + (((2 * ksg + hi) * 64) + db * 32 + l31) * 8);

        // S^T = K @ Q : lane holds scores for q, keys (r&3)+8*(r>>2)+4*hi (+32*ks)
        f16v s0, s1;
#pragma unroll
        for (int r = 0; r < 16; ++r) { s0[r] = 0.f; s1[r] = 0.f; }
#pragma unroll
        for (int kd = 0; kd < 4; ++kd) {
            s0 = __builtin_amdgcn_mfma_f32_32x32x16_bf16(kf[0][kd], qf[kd], s0, 0, 0, 0);
            s1 = __builtin_amdgcn_mfma_f32_32x32x16_bf16(kf[1][kd], qf[kd], s1, 0, 0, 0);
        }

        // lane-local row max (raw domain), combine halves with one shfl
        float mx = s0[0];
#pragma unroll
        for (int r = 1; r < 16; ++r) mx = fmaxf(mx, s0[r]);
#pragma unroll
        for (int r = 0; r < 16; ++r) mx = fmaxf(mx, s1[r]);
        mx = fmaxf(mx, __shfl_xor(mx, 32));
        const float mxl = mx * C;

        // defer-max (T13): only rescale when max grew by > 8 (2^8 headroom)
        const bool need = !__all(mxl - me <= 8.0f);
        float corr = 1.0f;
        if (need) {
            const float mnew = fmaxf(me, mxl);
            corr = EXP2F(me - mnew);
            me = mnew;
        }

        // P = 2^(s*C - me), row-sum; overwrite s-regs with p
        float rs = 0.f;
#pragma unroll
        for (int r = 0; r < 16; ++r) { s0[r] = EXP2F(__fmaf_rn(s0[r], C, -me)); rs += s0[r]; }
#pragma unroll
        for (int r = 0; r < 16; ++r) { s1[r] = EXP2F(__fmaf_rn(s1[r], C, -me)); rs += s1[r]; }
        rs += __shfl_xor(rs, 32);
        if (need) {
            lr = lr * corr + rs;
#pragma unroll
            for (int r = 0; r < 16; ++r) { O0[r] *= corr; O1[r] *= corr; }
        } else {
            lr += rs;
        }

        // Build P^T B-frags (col=q, k=key): pack reg-pairs to bf16x2,
        // exchange halves via shfl_xor(32), select own/partner per hi.
        s16v8 pb[2][2];
#pragma unroll
        for (int ks = 0; ks < 2; ++ks) {
            unsigned int u[8], su[8];
#pragma unroll
            for (int i = 0; i < 8; ++i) {
                const float plo = (ks == 0) ? s0[2 * i] : s1[2 * i];
                const float phi = (ks == 0) ? s0[2 * i + 1] : s1[2 * i + 1];
                u[i] = packbf2(plo, phi);
            }
#pragma unroll
            for (int i = 0; i < 8; ++i) su[i] = (unsigned int)__shfl_xor((int)u[i], 32);
#pragma unroll
            for (int kk = 0; kk < 2; ++kk) {
                const int base = 4 * kk + 2 * hi;
                union { unsigned int w[4]; s16v8 s; } f;
                f.w[0] = hi ? su[base] : u[base];
                f.w[1] = hi ? su[base + 1] : u[base + 1];
                f.w[2] = hi ? u[base] : su[base];
                f.w[3] = hi ? u[base + 1] : su[base + 1];
                pb[ks][kk] = f.s;
            }
        }

        // O^T += V^T @ P^T  (k = 16 keys per mfma; ksg = ks*2+kk)
#pragma unroll
        for (int ksg = 0; ksg < 4; ++ksg) {
            O0 = __builtin_amdgcn_mfma_f32_32x32x16_bf16(vf[0][ksg], pb[ksg >> 1][ksg & 1], O0, 0, 0, 0);
            O1 = __builtin_amdgcn_mfma_f32_32x32x16_bf16(vf[1][ksg], pb[ksg >> 1][ksg & 1], O1, 0, 0, 0);
        }

        __builtin_amdgcn_s_barrier();  // all waves done reading buf[cur]
        cur ^= 1;
    }
#undef STAGE

    // ---- epilogue: drain stray prefetch writes, then bounce O^T through
    // per-wave XOR-swizzled LDS for 16B-coalesced ctx stores.
    WAIT_VM0();                      // last (clamped) STAGE writes landed
    __builtin_amdgcn_s_barrier();    // ...for ALL waves, before LDS reuse

    const float inv = 1.0f / lr;
    unsigned short* mybuf = Sh + wv * 2048;  // 4KB/wave: 32 rows x 128B
#pragma unroll
    for (int db = 0; db < 2; ++db) {
        const f16v Ocur = db ? O1 : O0;
#pragma unroll
        for (int g2 = 0; g2 < 4; ++g2) {
            uint2 w;
            w.x = packbf2(Ocur[4 * g2 + 0] * inv, Ocur[4 * g2 + 1] * inv);
            w.y = packbf2(Ocur[4 * g2 + 2] * inv, Ocur[4 * g2 + 3] * inv);
            const int off = db * 64 + g2 * 16 + hi * 8;  // byte off in 128B row
            *(uint2*)((char*)mybuf + l31 * 128 + (off ^ ((l31 & 7) << 4))) = w;
        }
    }
    __syncthreads();  // order writes before reads (and across-wave reuse safety)

    const int r = l >> 1, h2 = l & 1;
    const int qrow = qblk * 256 + wv * 32 + r;
    const int b_ = bh >> 4, h_ = bh & 15;
    unsigned short* crow = ctx + ((size_t)b_ * SS + qrow) * DM + h_ * DK + h2 * 32;
#pragma unroll
    for (int j = 0; j < 4; ++j) {
        const int off = (h2 * 64 + j * 16) ^ ((r & 7) << 4);
        u16v8 v = *(const u16v8*)((const char*)mybuf + r * 128 + off);
        *(u16v8*)(crow + j * 8) = v;
    }
#undef ShK
#undef ShV
}

// ---------------------------------------------------------------------------
extern "C" void kernel_launch(void* const* d_in, const int* in_sizes, int n_in,
                              void* d_out, int out_size, void* d_ws, size_t ws_size,
                              hipStream_t stream) {
    const float* query = (const float*)d_in[0];
    const float* key_  = (const float*)d_in[1];
    const float* value = (const float*)d_in[2];
    const float* w_q = (const float*)d_in[3];
    const float* b_q = (const float*)d_in[4];
    const float* w_k = (const float*)d_in[5];
    const float* b_k = (const float*)d_in[6];
    const float* w_v = (const float*)d_in[7];
    const float* b_v = (const float*)d_in[8];
    const float* w_o = (const float*)d_in[9];
    const float* b_o = (const float*)d_in[10];

    unsigned short* ws = (unsigned short*)d_ws;
    const size_t NX = (size_t)MTOT * DM;  // 8,388,608
    const size_t NW = (size_t)DM * DM;    // 1,048,576
    unsigned short* xq  = ws;
    unsigned short* xk  = xq + NX;
    unsigned short* xv  = xk + NX;
    unsigned short* wqb = xv + NX;
    unsigned short* wkb = wqb + NW;
    unsigned short* wvb = wkb + NW;
    unsigned short* wob = wvb + NW;
    unsigned short* Qp  = wob + NW;
    unsigned short* Kp  = Qp + NX;
    unsigned short* VpT = Kp + NX;
    unsigned short* ctx = xq;  // alias: xq dead after gemm_qkv
    // high-water: 6*NX + 4*NW = 104 MB

    Src7 sp;
    sp.p[0] = query; sp.p[1] = key_; sp.p[2] = value;
    sp.p[3] = w_q; sp.p[4] = w_k; sp.p[5] = w_v; sp.p[6] = w_o;
    cvt_all<<<14336, 256, 0, stream>>>(sp, ws);

    QkvArgs qa;
    qa.X[0] = xq;  qa.X[1] = xk;  qa.X[2] = xv;
    qa.W[0] = wqb; qa.W[1] = wkb; qa.W[2] = wvb;
    qa.bias[0] = b_q; qa.bias[1] = b_k; qa.bias[2] = b_v;
    qa.Y[0] = Qp; qa.Y[1] = Kp; qa.Y[2] = VpT;
    gemm_qkv<<<dim3(MTOT / 128, DM / 128, 3), 256, 0, stream>>>(qa);

    attn_mfma32<<<dim3(BB * NH, SS / 256), 512, 0, stream>>>(Qp, Kp, VpT, ctx);

    gemm_out<<<dim3(MTOT / 128, DM / 128), 256, 0, stream>>>(ctx, wob, b_o, (float*)d_out);
}